// Round 7
// baseline (2023.270 us; speedup 1.0000x reference)
//
#include <hip/hip_runtime.h>
#include <hip/hip_fp16.h>

#define TT 2048
#define BB 256
#define HH 64
#define II 60
#define OO 12
#define LL 3

typedef _Float16 h2 __attribute__((ext_vector_type(2)));
typedef unsigned u32x4 __attribute__((ext_vector_type(4)));

#ifndef __has_builtin
#define __has_builtin(x) 0
#endif

#if __has_builtin(__builtin_amdgcn_fdot2)
__device__ __forceinline__ float dot2(unsigned a, unsigned b, float acc) {
  return __builtin_amdgcn_fdot2(__builtin_bit_cast(h2, a), __builtin_bit_cast(h2, b), acc, false);
}
#else
// clang fuses cvt_f32_f16 + fma into v_fma_mix_f32 on CDNA
__device__ __forceinline__ float dot2(unsigned a, unsigned b, float acc) {
  h2 A = __builtin_bit_cast(h2, a), B = __builtin_bit_cast(h2, b);
  acc = fmaf((float)A[0], (float)B[0], acc);
  acc = fmaf((float)A[1], (float)B[1], acc);
  return acc;
}
#endif

__device__ __forceinline__ float sigf(float x)   { return 1.f / (1.f + __expf(-x)); }
__device__ __forceinline__ float tanhf2(float x) { return 2.f / (1.f + __expf(-2.f * x)) - 1.f; }

// 64-MAC dot against a register row (8 x u32x4 = 64 f16), 4 chains.
__device__ __forceinline__ float dotreg(const u32x4 (&P)[8], const unsigned* w, float acc) {
  float a0 = acc, a1 = 0.f, a2 = 0.f, a3 = 0.f;
#pragma unroll
  for (int j = 0; j < 8; j++) {
    a0 = dot2(P[j][0], w[4 * j + 0], a0);
    a1 = dot2(P[j][1], w[4 * j + 1], a1);
    a2 = dot2(P[j][2], w[4 * j + 2], a2);
    a3 = dot2(P[j][3], w[4 * j + 3], a3);
  }
  return (a0 + a1) + (a2 + a3);
}

// 64-MAC dot against an LDS f16 row (uniform address -> broadcast reads).
__device__ __forceinline__ float dotlds(const _Float16* row, const unsigned* w, float acc) {
  const unsigned* rp = (const unsigned*)row;
  float a0 = acc, a1 = 0.f, a2 = 0.f, a3 = 0.f;
#pragma unroll
  for (int j = 0; j < 32; j += 4) {
    a0 = dot2(rp[j + 0], w[j + 0], a0);
    a1 = dot2(rp[j + 1], w[j + 1], a1);
    a2 = dot2(rp[j + 2], w[j + 2], a2);
    a3 = dot2(rp[j + 3], w[j + 3], a3);
  }
  return (a0 + a1) + (a2 + a3);
}

// ---- pre-pass: x [B,T,60] fp32 -> xh [B,T,64] f16 (zero-padded) ----
__global__ __launch_bounds__(256)
void xcvt(const float* __restrict__ x, unsigned* __restrict__ xh) {
  long v = (long)blockIdx.x * 256 + threadIdx.x;   // half2 units (B*T*32)
  int  c2 = (int)(v & 31);
  long row = v >> 5;
  int k0 = 2 * c2, k1 = k0 + 1;
  const float* xr = x + row * II;
  float f0 = (k0 < II) ? xr[k0] : 0.f;
  float f1 = (k1 < II) ? xr[k1] : 0.f;
  h2 p; p[0] = (_Float16)f0; p[1] = (_Float16)f1;
  xh[v] = __builtin_bit_cast(unsigned, p);
}

// ---- fused 3-layer wavefront LSTM (round-4 schedule, proven) ----
// Block b = batch b. 768 threads = 3 teams x 256 (team l = layer l).
// Phase s: team l (A) wave l combines t=s-l from gbuf, publishes h to
// hbf[l][s&3]; (B) all 4 waves compute gates(t+1). 2 barriers/phase.
// amdgpu_waves_per_eu(3,3): pin the scheduler's occupancy target so the
// 168-VGPR budget is actually used for arch VGPRs — rounds 1-4 show the
// default (min-only from launch_bounds) compresses to ~84 arch VGPRs and
// parks the resident weights in AGPRs, paying v_accvgpr_read per use.
__global__ __launch_bounds__(768) __attribute__((amdgpu_waves_per_eu(3, 3)))
void lstm3_fused(const unsigned* __restrict__ xh,
                 _Float16* __restrict__ hs,
                 const float* __restrict__ Wih0, const float* __restrict__ Whh0,
                 const float* __restrict__ bih0, const float* __restrict__ bhh0,
                 const float* __restrict__ Wih1, const float* __restrict__ Whh1,
                 const float* __restrict__ bih1, const float* __restrict__ bhh1,
                 const float* __restrict__ Wih2, const float* __restrict__ Whh2,
                 const float* __restrict__ bih2, const float* __restrict__ bhh2,
                 const float* __restrict__ h0, const float* __restrict__ c0,
                 float* __restrict__ hn, float* __restrict__ cn) {
  const int b   = blockIdx.x;
  const int tid = threadIdx.x;
  const int l   = tid >> 8;
  const int g   = tid & 255;
  const int u   = g & 63;
  const int w   = g >> 6;          // wave-in-team
  const bool cw = (w == l);        // combine wave: SIMDs 0,1,2 across teams

  __shared__ float gbuf[LL][2][256];
  __shared__ __align__(16) _Float16 hbf[LL][4][HH];

  const float* Wih = (l == 0) ? Wih0 : (l == 1) ? Wih1 : Wih2;
  const float* Whh = (l == 0) ? Whh0 : (l == 1) ? Whh1 : Whh2;
  const float* bih = (l == 0) ? bih0 : (l == 1) ? bih1 : bih2;
  const float* bhh = (l == 0) ? bhh0 : (l == 1) ? bhh1 : bhh2;
  const int IN = (l == 0) ? II : HH;

  // resident weights: 64 uints (f16x2 pairs)
  unsigned wx[32], wh[32];
#pragma unroll
  for (int j = 0; j < 32; j++) {
    int k0 = 2 * j, k1 = k0 + 1;
    float f0 = (k0 < IN) ? Wih[(size_t)g * IN + k0] : 0.f;
    float f1 = (k1 < IN) ? Wih[(size_t)g * IN + k1] : 0.f;
    h2 p; p[0] = (_Float16)f0; p[1] = (_Float16)f1;
    wx[j] = __builtin_bit_cast(unsigned, p);
    h2 q; q[0] = (_Float16)Whh[(size_t)g * HH + k0]; q[1] = (_Float16)Whh[(size_t)g * HH + k1];
    wh[j] = __builtin_bit_cast(unsigned, q);
  }
#pragma unroll
  for (int j = 0; j < 32; j++) {
    asm volatile("" : "+v"(wx[j]));
    asm volatile("" : "+v"(wh[j]));
  }
  const float bias = bih[g] + bhh[g];

  float hreg = h0[(l * BB + b) * HH + u];
  float creg = c0[(l * BB + b) * HH + u];

  const unsigned* xbase = xh + (long)b * TT * 32;

  // ---- prologue: seed h0 rows (slot (l-1)&3); team 0 computes gates_0(0) ----
  if (cw) hbf[l][(l + 3) & 3][u] = (_Float16)hreg;
  __syncthreads();

  u32x4 PA[8], PB[8];
  if (l == 0) {
    u32x4 T0[8];
    const u32x4* xr0 = (const u32x4*)(xbase + 0 * 32);
    const u32x4* xr1 = (const u32x4*)(xbase + 1 * 32);
    const u32x4* xr2 = (const u32x4*)(xbase + 2 * 32);
#pragma unroll
    for (int j = 0; j < 8; j++) { T0[j] = xr0[j]; PA[j] = xr1[j]; PB[j] = xr2[j]; }
    float acc = dotreg(T0, wx, bias);
    acc = dotlds(&hbf[0][3][0], wh, acc);
    gbuf[0][0][g] = acc;                              // gates_0(0)
  }
  __syncthreads();

  // ---- phase body (round-4 structure) ----
  auto phase = [&](int s, u32x4 (&cur)[8]) {
    const int t    = s - l;
    const int slot = s & 3;

    // Stage A: combine (one wave per team)
    if (cw && t >= 0 && t < TT) {
      const float* gb = &gbuf[l][s & 1][0];
      float g0 = gb[u], g1 = gb[64 + u], g2 = gb[128 + u], g3 = gb[192 + u];
      creg = sigf(g1) * creg + sigf(g0) * tanhf2(g2);
      hreg = sigf(g3) * tanhf2(creg);
      hbf[l][slot][u] = (_Float16)hreg;
      if (l == 2) hs[((long)b * TT + t) * HH + u] = (_Float16)hreg;
      if (t == TT - 1) {
        hn[(l * BB + b) * HH + u] = hreg;
        cn[(l * BB + b) * HH + u] = creg;
      }
    }
    __syncthreads();   // hbf rows for this phase ready

    // Stage B: gates(t+1)
    const int tn = t + 1;
    if (tn >= 0 && tn < TT) {
      float acc;
      if (l == 0) acc = dotreg(cur, wx, bias);
      else        acc = dotlds(&hbf[l - 1][slot][0], wx, bias);
      acc = dotlds(&hbf[l][slot][0], wh, acc);
      gbuf[l][(s + 1) & 1][g] = acc;
      if (l == 0 && s + 3 < TT) {                     // refill: consumed at phase s+2
        const u32x4* xr = (const u32x4*)(xbase + (long)(s + 3) * 32);
#pragma unroll
        for (int j = 0; j < 8; j++) cur[j] = xr[j];
      }
    }
    __syncthreads();   // gbuf(t+1) ready
  };

  for (int s = 0; s < TT + 2; s += 2) {
    phase(s,     PA);
    phase(s + 1, PB);
  }
}

// ---- output projection: y[b,t,:] = W_out @ h_row + b_out ----
__global__ __launch_bounds__(256)
void oproj(const _Float16* __restrict__ hs,
           const float* __restrict__ Wout,
           const float* __restrict__ bout,
           float* __restrict__ y) {
  __shared__ float Wo[OO * HH];
  __shared__ float bo[OO];
  const int tid = threadIdx.x;
  for (int i = tid; i < OO * HH; i += 256) Wo[i] = Wout[i];
  if (tid < OO) bo[tid] = bout[tid];
  __syncthreads();

  const long r = (long)blockIdx.x * 256 + tid;  // r = b*T + t
  const uint4* h4 = (const uint4*)(hs + r * HH);
  float hf[HH];
#pragma unroll
  for (int jj = 0; jj < 8; jj++) {
    uint4 q = h4[jj];
    h2 p0 = __builtin_bit_cast(h2, q.x), p1 = __builtin_bit_cast(h2, q.y);
    h2 p2 = __builtin_bit_cast(h2, q.z), p3 = __builtin_bit_cast(h2, q.w);
    hf[8 * jj + 0] = (float)p0[0]; hf[8 * jj + 1] = (float)p0[1];
    hf[8 * jj + 2] = (float)p1[0]; hf[8 * jj + 3] = (float)p1[1];
    hf[8 * jj + 4] = (float)p2[0]; hf[8 * jj + 5] = (float)p2[1];
    hf[8 * jj + 6] = (float)p3[0]; hf[8 * jj + 7] = (float)p3[1];
  }

  float out[OO];
#pragma unroll
  for (int o = 0; o < OO; o++) {
    float a0 = bo[o], a1 = 0.f, a2 = 0.f, a3 = 0.f;
#pragma unroll
    for (int k = 0; k < HH; k += 4) {
      a0 += hf[k + 0] * Wo[o * HH + k + 0];
      a1 += hf[k + 1] * Wo[o * HH + k + 1];
      a2 += hf[k + 2] * Wo[o * HH + k + 2];
      a3 += hf[k + 3] * Wo[o * HH + k + 3];
    }
    out[o] = (a0 + a1) + (a2 + a3);
  }
  float4* yp = (float4*)(y + r * OO);
#pragma unroll
  for (int q = 0; q < 3; q++)
    yp[q] = make_float4(out[4 * q], out[4 * q + 1], out[4 * q + 2], out[4 * q + 3]);
}

extern "C" void kernel_launch(void* const* d_in, const int* in_sizes, int n_in,
                              void* d_out, int out_size, void* d_ws, size_t ws_size,
                              hipStream_t stream) {
  const float* x    = (const float*)d_in[0];
  const float* h0   = (const float*)d_in[1];
  const float* c0   = (const float*)d_in[2];
  const float* Wih0 = (const float*)d_in[3];
  const float* Whh0 = (const float*)d_in[4];
  const float* bih0 = (const float*)d_in[5];
  const float* bhh0 = (const float*)d_in[6];
  const float* Wih1 = (const float*)d_in[7];
  const float* Whh1 = (const float*)d_in[8];
  const float* bih1 = (const float*)d_in[9];
  const float* bhh1 = (const float*)d_in[10];
  const float* Wih2 = (const float*)d_in[11];
  const float* Whh2 = (const float*)d_in[12];
  const float* bih2 = (const float*)d_in[13];
  const float* bhh2 = (const float*)d_in[14];
  const float* Wout = (const float*)d_in[15];
  const float* bout = (const float*)d_in[16];

  float* y  = (float*)d_out;
  float* hn = y + (size_t)BB * TT * OO;
  float* cn = hn + (size_t)LL * BB * HH;

  // ws layout (as round 4): [0, 64MiB) = xh (f16 padded x), then hs (f16 h2)
  unsigned*  xh = (unsigned*)d_ws;
  _Float16*  hs = (_Float16*)((char*)d_ws + (size_t)BB * TT * HH * 2 * sizeof(_Float16));

  xcvt<<<dim3(BB * TT * 32 / 256), dim3(256), 0, stream>>>(x, xh);
  lstm3_fused<<<dim3(BB), dim3(768), 0, stream>>>(xh, hs,
      Wih0, Whh0, bih0, bhh0, Wih1, Whh1, bih1, bhh1, Wih2, Whh2, bih2, bhh2,
      h0, c0, hn, cn);
  oproj<<<dim3(BB * TT / 256), dim3(256), 0, stream>>>(hs, Wout, bout, y);
}